// Round 3
// baseline (1772.051 us; speedup 1.0000x reference)
//
#include <hip/hip_runtime.h>

#define DIM   64
#define HW    4096      // 64*64 spatial per batch
#define NEMB  1024

// ---------------- init: zero counts + errsum, precompute enorm ----------------
// numpy pairwise-8 accumulator order (bit-exact vs reference).
__global__ __launch_bounds__(128) void vq_init(const float* __restrict__ emb,
                                               unsigned int* __restrict__ counts,
                                               float* __restrict__ errsum,
                                               float* __restrict__ enorm) {
    const int k = blockIdx.x * 128 + threadIdx.x;
    counts[k] = 0u;
    if (k == 0) *errsum = 0.0f;
    const float* e = emb + k * 64;
    float a[8] = {0,0,0,0,0,0,0,0};
    #pragma unroll
    for (int c = 0; c < 16; ++c) {
        float4 v = *(const float4*)(e + c * 4);
        a[(4*c+0) & 7] += v.x * v.x;
        a[(4*c+1) & 7] += v.y * v.y;
        a[(4*c+2) & 7] += v.z * v.z;
        a[(4*c+3) & 7] += v.w * v.w;
    }
    enorm[k] = ((a[0]+a[1]) + (a[2]+a[3])) + ((a[4]+a[5]) + (a[6]+a[7]));
}

// ---------------- main ----------------
// grid 512 x 256. Block: 128 samples, loops 8 k-tiles of 128 embeddings.
// zt chunk-major [dc][x] (lane-linear staging); et row-major XOR-swizzled.
__global__ __launch_bounds__(256) __attribute__((amdgpu_waves_per_eu(2, 2)))
void vq_main(const float* __restrict__ z, const float* __restrict__ emb,
             const float* __restrict__ enorm,
             float* __restrict__ out, unsigned int* __restrict__ counts,
             float* __restrict__ errsum)
{
    __shared__ float zt[16 * 512];   // chunk dc, sample x -> zt[dc*512 + x*4 .. +3]
    __shared__ float et[128 * 64];   // row r: 256B, chunk dc at slot dc ^ (r>>3)
    __shared__ float en_all[1024];
    __shared__ float znorm_s[128];
    __shared__ float md_sh[128];
    __shared__ int   idx_sh[128];

    const int t   = threadIdx.x;
    const int n0  = blockIdx.x * 128;
    const int bb  = n0 >> 12;        // batch index
    const int hw0 = n0 & 4095;
    const float* zb = z + bb * (DIM * HW) + hw0;   // + d*HW + x

    // ---- stage all 1024 enorms (one float4/thread) ----
    *(float4*)&en_all[t * 4] = *(const float4*)&enorm[t * 4];

    // ---- stage z tile: global [d][x] -> LDS chunk-major [dc][x] ----
    {
        const int x = t & 127;
        const int g = t >> 7;
        #pragma unroll
        for (int it = 0; it < 8; ++it) {
            const int dc = g * 8 + it;
            float4 v;
            v.x = zb[(dc * 4 + 0) * HW + x];
            v.y = zb[(dc * 4 + 1) * HW + x];
            v.z = zb[(dc * 4 + 2) * HW + x];
            v.w = zb[(dc * 4 + 3) * HW + x];
            *(float4*)&zt[dc * 512 + x * 4] = v;   // lane-linear: conflict-free
        }
    }

    // ---- stage e tile 0 (reg round-trip; transient) ----
    const int tr  = t >> 4;    // 0..15
    const int dcS = t & 15;
    float4 stg[8];
    {
        const float* gp = emb + tr * 64 + dcS * 4;
        #pragma unroll
        for (int ii = 0; ii < 8; ++ii) stg[ii] = *(const float4*)(gp + ii * 1024);
    }
    #pragma unroll
    for (int ii = 0; ii < 8; ++ii) {
        const int r = ii * 16 + tr;
        *(float4*)&et[r * 64 + ((dcS ^ (r >> 3)) << 2)] = stg[ii];
    }
    __syncthreads();   // zt + en_all + et tile0 visible

    // ---- znorm, numpy pairwise-8 order (chunk-major zt reads: lane-linear) ----
    if (t < 128) {
        const int x = t;
        float a[8] = {0,0,0,0,0,0,0,0};
        #pragma unroll
        for (int dc = 0; dc < 16; ++dc) {
            float4 v = *(const float4*)&zt[dc * 512 + x * 4];
            a[(4*dc+0) & 7] += v.x * v.x;
            a[(4*dc+1) & 7] += v.y * v.y;
            a[(4*dc+2) & 7] += v.z * v.z;
            a[(4*dc+3) & 7] += v.w * v.w;
        }
        znorm_s[x] = ((a[0]+a[1]) + (a[2]+a[3])) + ((a[4]+a[5]) + (a[6]+a[7]));
    }
    __syncthreads();

    const int kl = t & 15;   // k-lane (0..15)
    const int ng = t >> 4;   // n-group (0..15)
    const float* ztp = &zt[ng * 32];    // + dc*512 + i*4
    const float* etp = &et[kl * 512];   // + j*64 + ((dc^kl)<<2)

    float zn[8];
    #pragma unroll
    for (int i = 0; i < 8; ++i) zn[i] = znorm_s[ng * 8 + i];

    float mval[8];
    int   midx[8];
    #pragma unroll
    for (int i = 0; i < 8; ++i) { mval[i] = __builtin_inff(); midx[i] = 0; }

    for (int kt = 0; kt < 8; ++kt) {
        const int kbase = kt * 128;

        float en[8];
        {
            float4 ea = *(const float4*)&en_all[kbase + kl * 8];
            float4 eb = *(const float4*)&en_all[kbase + kl * 8 + 4];
            en[0]=ea.x; en[1]=ea.y; en[2]=ea.z; en[3]=ea.w;
            en[4]=eb.x; en[5]=eb.y; en[6]=eb.z; en[7]=eb.w;
        }

        float acc[8][8];
        #pragma unroll
        for (int i = 0; i < 8; ++i)
            #pragma unroll
            for (int j = 0; j < 8; ++j) acc[i][j] = 0.0f;

        // ---- dot loop: A/B software-pipelined fragments, fully unrolled ----
        float4 zA[8], eA[8], zB[8], eB[8];
        #pragma unroll
        for (int i = 0; i < 8; ++i) zA[i] = *(const float4*)(ztp + i * 4);
        {
            const int o = (kl << 2);   // dc=0
            #pragma unroll
            for (int j = 0; j < 8; ++j) eA[j] = *(const float4*)(etp + j * 64 + o);
        }

#define VQ_STEP(DC, ZC, EC, ZN, EN, PRE)                                        \
        {                                                                       \
            if (PRE) {                                                          \
                const int o = (((DC + 1) ^ kl) << 2);                           \
                _Pragma("unroll")                                               \
                for (int j = 0; j < 8; ++j)                                     \
                    EN[j] = *(const float4*)(etp + j * 64 + o);                 \
                _Pragma("unroll")                                               \
                for (int i = 0; i < 8; ++i)                                     \
                    ZN[i] = *(const float4*)(ztp + (DC + 1) * 512 + i * 4);     \
            }                                                                   \
            _Pragma("unroll")                                                   \
            for (int i = 0; i < 8; ++i) {                                       \
                _Pragma("unroll")                                               \
                for (int j = 0; j < 8; ++j) {                                   \
                    acc[i][j] = fmaf(ZC[i].x, EC[j].x, acc[i][j]);              \
                    acc[i][j] = fmaf(ZC[i].y, EC[j].y, acc[i][j]);              \
                    acc[i][j] = fmaf(ZC[i].z, EC[j].z, acc[i][j]);              \
                    acc[i][j] = fmaf(ZC[i].w, EC[j].w, acc[i][j]);              \
                }                                                               \
            }                                                                   \
        }

        VQ_STEP(0,  zA, eA, zB, eB, true)
        VQ_STEP(1,  zB, eB, zA, eA, true)
        VQ_STEP(2,  zA, eA, zB, eB, true)
        VQ_STEP(3,  zB, eB, zA, eA, true)
        VQ_STEP(4,  zA, eA, zB, eB, true)
        VQ_STEP(5,  zB, eB, zA, eA, true)
        VQ_STEP(6,  zA, eA, zB, eB, true)
        VQ_STEP(7,  zB, eB, zA, eA, true)
        VQ_STEP(8,  zA, eA, zB, eB, true)
        VQ_STEP(9,  zB, eB, zA, eA, true)
        VQ_STEP(10, zA, eA, zB, eB, true)
        VQ_STEP(11, zB, eB, zA, eA, true)
        VQ_STEP(12, zA, eA, zB, eB, true)
        VQ_STEP(13, zB, eB, zA, eA, true)
        VQ_STEP(14, zA, eA, zB, eB, true)
        VQ_STEP(15, zB, eB, zA, eA, false)
#undef VQ_STEP

        // ---- issue next tile's global loads (latency hides under argmin+barrier) ----
        if (kt < 7) {
            const float* gp = emb + (kbase + 128) * 64 + tr * 64 + dcS * 4;
            #pragma unroll
            for (int ii = 0; ii < 8; ++ii) stg[ii] = *(const float4*)(gp + ii * 1024);
        }

        // ---- distances + running argmin (ascending k, strict < tie-break) ----
        #pragma unroll
        for (int j = 0; j < 8; ++j) {
            const int kg = kbase + kl * 8 + j;
            #pragma unroll
            for (int i = 0; i < 8; ++i) {
                const float tt   = zn[i] + en[j];
                const float dist = fmaf(-2.0f, acc[i][j], tt);
                if (dist < mval[i]) { mval[i] = dist; midx[i] = kg; }
            }
        }

        __syncthreads();   // done reading et (drains stg loads too)
        if (kt < 7) {
            #pragma unroll
            for (int ii = 0; ii < 8; ++ii) {
                const int r = ii * 16 + tr;
                *(float4*)&et[r * 64 + ((dcS ^ (r >> 3)) << 2)] = stg[ii];
            }
            __syncthreads();   // next et tile visible
        }
    }

    // ---- cross-lane argmin over 16 k-lanes (tie-break: smaller k) ----
    #pragma unroll
    for (int i = 0; i < 8; ++i) {
        float m = mval[i]; int id = midx[i];
        #pragma unroll
        for (int mask = 1; mask <= 8; mask <<= 1) {
            float m2 = __shfl_xor(m, mask, 64);
            int   i2 = __shfl_xor(id, mask, 64);
            if (m2 < m || (m2 == m && i2 < id)) { m = m2; id = i2; }
        }
        if (kl == 0) { md_sh[ng*8 + i] = m; idx_sh[ng*8 + i] = id; }
    }
    __syncthreads();

    // ---- histogram + error sum (min distance == ||z-e||^2) ----
    if (t < 128) atomicAdd(&counts[idx_sh[t]], 1u);
    if (t < 64) {
        float s = md_sh[t] + md_sh[t + 64];
        #pragma unroll
        for (int off = 32; off >= 1; off >>= 1) s += __shfl_down(s, off, 64);
        if (t == 0) atomicAdd(errsum, s);
    }

    // ---- epilogue: out = z + (q - z), exact ref rounding ----
    {
        const int x  = t & 127;
        const int cg = t >> 7;
        const int idx = idx_sh[x];
        const float* er = emb + idx * 64;
        float* ob = out + bb * (DIM * HW) + hw0 + x;
        #pragma unroll
        for (int cq = 0; cq < 8; ++cq) {
            const int c  = cg * 32 + cq * 4;
            const int dc = c >> 2;
            float4 e4 = *(const float4*)&er[c];
            float4 z4 = *(const float4*)&zt[dc * 512 + x * 4];
            ob[(c+0) * HW] = z4.x + (e4.x - z4.x);
            ob[(c+1) * HW] = z4.y + (e4.y - z4.y);
            ob[(c+2) * HW] = z4.z + (e4.z - z4.z);
            ob[(c+3) * HW] = z4.w + (e4.w - z4.w);
        }
    }
}

// ---------------- finalize: scalars ----------------
__global__ __launch_bounds__(256) void vq_fin(const unsigned int* __restrict__ counts,
                                              const float* __restrict__ errsum,
                                              float* __restrict__ scal)
{
    __shared__ float part[4];
    const int t = threadIdx.x;
    float s = 0.0f;
    for (int k = t; k < NEMB; k += 256) {
        float p = (float)counts[k] * (1.0f / 65536.0f);
        s += p * logf(p + 1e-10f);
    }
    #pragma unroll
    for (int off = 32; off >= 1; off >>= 1) s += __shfl_down(s, off, 64);
    if ((t & 63) == 0) part[t >> 6] = s;
    __syncthreads();
    if (t == 0) {
        float tot = (part[0] + part[1]) + (part[2] + part[3]);
        float es  = *errsum;
        scal[0] = 1.25f * (es * (1.0f / 4194304.0f));  // loss = 1.25 * mse
        scal[1] = expf(-tot);                          // perplexity
        scal[2] = es * (1.0f / 65536.0f);              // avg_error
    }
}

extern "C" void kernel_launch(void* const* d_in, const int* in_sizes, int n_in,
                              void* d_out, int out_size, void* d_ws, size_t ws_size,
                              hipStream_t stream) {
    const float* z   = (const float*)d_in[0];
    const float* emb = (const float*)d_in[1];
    float* out = (float*)d_out;
    unsigned int* counts = (unsigned int*)d_ws;
    float* errsum = (float*)((char*)d_ws + 4096);
    float* enorm  = (float*)((char*)d_ws + 8192);

    vq_init<<<8, 128, 0, stream>>>(emb, counts, errsum, enorm);
    vq_main<<<512, 256, 0, stream>>>(z, emb, enorm, out, counts, errsum);
    vq_fin<<<1, 256, 0, stream>>>(counts, errsum, out + 4194304);
}

// Round 4
// 149.906 us; speedup vs baseline: 11.8210x; 11.8210x over previous
//
#include <hip/hip_runtime.h>
#include <stdint.h>

#define HW     4096      // 64*64 spatial per batch
#define NEMB   1024
#define ZPLANE 576       // floats per zt plane (128 samples, skewed)
// float offset of sample x within a zt plane: (x + (x>>3)) * 4  -> bank-skewed, 16B aligned
#define ZOFF(x) ((((x) + ((x) >> 3)) << 2))

// direct global->LDS DMA, 16B per lane (linear dest = wave base + lane*16)
__device__ __forceinline__ void gload_lds16(const float* g, float* l) {
    __builtin_amdgcn_global_load_lds(
        (const __attribute__((address_space(1))) void*)(uintptr_t)g,
        (__attribute__((address_space(3))) void*)(uintptr_t)l, 16, 0, 0);
}

// ---------------- init: zero counts + errsum, precompute enorm ----------------
// numpy pairwise-8 accumulator order (verified bit-exact in r3).
__global__ __launch_bounds__(128) void vq_init(const float* __restrict__ emb,
                                               unsigned int* __restrict__ counts,
                                               float* __restrict__ errsum,
                                               float* __restrict__ enorm) {
    const int k = blockIdx.x * 128 + threadIdx.x;
    counts[k] = 0u;
    if (k == 0) *errsum = 0.0f;
    const float* e = emb + k * 64;
    float a[8] = {0,0,0,0,0,0,0,0};
    #pragma unroll
    for (int c = 0; c < 16; ++c) {
        float4 v = *(const float4*)(e + c * 4);
        a[(4*c+0) & 7] += v.x * v.x;
        a[(4*c+1) & 7] += v.y * v.y;
        a[(4*c+2) & 7] += v.z * v.z;
        a[(4*c+3) & 7] += v.w * v.w;
    }
    enorm[k] = ((a[0]+a[1]) + (a[2]+a[3])) + ((a[4]+a[5]) + (a[6]+a[7]));
}

// ---------------- main ----------------
// grid 512 x 256. Block: 128 samples, 8 k-tiles of 128 embeddings.
__global__ __launch_bounds__(256, 2)
void vq_main(const float* __restrict__ z, const float* __restrict__ emb,
             const float* __restrict__ enorm,
             float* __restrict__ out, unsigned int* __restrict__ counts,
             float* __restrict__ errsum)
{
    __shared__ float zt[16 * ZPLANE];   // chunk-major, skewed: zt[dc*ZPLANE + ZOFF(x)]
    __shared__ float et[128 * 64];      // row r: slot s holds chunk s ^ (r>>3)
    __shared__ float en_all[NEMB];
    __shared__ float znorm_s[128];
    __shared__ float md_sh[128];
    __shared__ int   idx_sh[128];

    const int t   = threadIdx.x;
    const int n0  = blockIdx.x * 128;
    const int bb  = n0 >> 12;        // batch index
    const int hw0 = n0 & 4095;
    const float* zb = z + bb * (64 * HW) + hw0;   // + d*HW + x

    // ---- issue et tile 0 via global_load_lds (pre-swizzled source, linear dest) ----
    {
        #pragma unroll
        for (int it = 0; it < 8; ++it) {
            const int p  = it * 256 + t;             // float4 position 0..2047
            const int r  = p >> 4;                   // row 0..127
            const int dc = (p & 15) ^ (r >> 3);      // inverse swizzle on SOURCE
            gload_lds16(emb + r * 64 + dc * 4, et + p * 4);
        }
    }

    // ---- stage all 1024 enorms ----
    *(float4*)&en_all[t * 4] = *(const float4*)&enorm[t * 4];

    // ---- stage z tile: global [d][x] -> LDS chunk-major skewed ----
    {
        const int x  = t & 127;
        const int g  = t >> 7;
        const int xo = ZOFF(x);
        #pragma unroll
        for (int it = 0; it < 8; ++it) {
            const int dc = g * 8 + it;
            float4 v;
            v.x = zb[(dc * 4 + 0) * HW + x];
            v.y = zb[(dc * 4 + 1) * HW + x];
            v.z = zb[(dc * 4 + 2) * HW + x];
            v.w = zb[(dc * 4 + 3) * HW + x];
            *(float4*)&zt[dc * ZPLANE + xo] = v;
        }
    }
    __syncthreads();   // zt + et0 + en_all visible (vmcnt+lgkm drained)

    // ---- znorm, numpy pairwise-8 order ----
    if (t < 128) {
        const int xo = ZOFF(t);
        float a[8] = {0,0,0,0,0,0,0,0};
        #pragma unroll
        for (int dc = 0; dc < 16; ++dc) {
            float4 v = *(const float4*)&zt[dc * ZPLANE + xo];
            a[(4*dc+0) & 7] += v.x * v.x;
            a[(4*dc+1) & 7] += v.y * v.y;
            a[(4*dc+2) & 7] += v.z * v.z;
            a[(4*dc+3) & 7] += v.w * v.w;
        }
        znorm_s[t] = ((a[0]+a[1]) + (a[2]+a[3])) + ((a[4]+a[5]) + (a[6]+a[7]));
    }
    __syncthreads();

    const int kl = t & 15;   // k-lane (0..15)
    const int ng = t >> 4;   // n-group (0..15)
    const float* zp = zt + ng * 36;    // ZOFF(ng*8+i) = ng*36 + i*4
    const float* ep = et + kl * 512;   // row kl*8+j at +j*64; swizzle factor = kl

    float zn[8];
    #pragma unroll
    for (int i = 0; i < 8; ++i) zn[i] = znorm_s[ng * 8 + i];

    float mval[8];
    int   midx[8];
    #pragma unroll
    for (int i = 0; i < 8; ++i) { mval[i] = __builtin_inff(); midx[i] = 0; }

    #pragma unroll 1
    for (int kt = 0; kt < 8; ++kt) {
        const int kbase = kt << 7;

        float en[8];
        {
            float4 ea = *(const float4*)&en_all[kbase + kl * 8];
            float4 eb = *(const float4*)&en_all[kbase + kl * 8 + 4];
            en[0]=ea.x; en[1]=ea.y; en[2]=ea.z; en[3]=ea.w;
            en[4]=eb.x; en[5]=eb.y; en[6]=eb.z; en[7]=eb.w;
        }

        float acc[8][8];
        #pragma unroll
        for (int i = 0; i < 8; ++i)
            #pragma unroll
            for (int j = 0; j < 8; ++j) acc[i][j] = 0.0f;

        // dot: ascending-d FMA chain (bit-exact vs numpy/BLAS)
        #pragma unroll 4
        for (int dc = 0; dc < 16; ++dc) {
            const int eo = ((dc ^ kl) << 2);
            float4 ef[8];
            #pragma unroll
            for (int j = 0; j < 8; ++j) ef[j] = *(const float4*)(ep + j * 64 + eo);
            #pragma unroll
            for (int i = 0; i < 8; ++i) {
                float4 zf = *(const float4*)(zp + dc * ZPLANE + i * 4);
                #pragma unroll
                for (int j = 0; j < 8; ++j) {
                    acc[i][j] = fmaf(zf.x, ef[j].x, acc[i][j]);
                    acc[i][j] = fmaf(zf.y, ef[j].y, acc[i][j]);
                    acc[i][j] = fmaf(zf.z, ef[j].z, acc[i][j]);
                    acc[i][j] = fmaf(zf.w, ef[j].w, acc[i][j]);
                }
            }
        }

        // distances + running argmin (ascending k, strict < => first-index tie-break)
        #pragma unroll
        for (int j = 0; j < 8; ++j) {
            const int kg = kbase + kl * 8 + j;
            #pragma unroll
            for (int i = 0; i < 8; ++i) {
                const float tt   = zn[i] + en[j];
                const float dist = fmaf(-2.0f, acc[i][j], tt);
                if (dist < mval[i]) { mval[i] = dist; midx[i] = kg; }
            }
        }

        __syncthreads();   // all waves done reading et[kt]
        if (kt < 7) {
            #pragma unroll
            for (int it = 0; it < 8; ++it) {
                const int p  = it * 256 + t;
                const int r  = p >> 4;
                const int dc = (p & 15) ^ (r >> 3);
                gload_lds16(emb + (kbase + 128 + r) * 64 + dc * 4, et + p * 4);
            }
            __syncthreads();   // vmcnt drained -> et[kt+1] ready
        }
    }

    // ---- cross-lane argmin over 16 k-lanes (tie-break: smaller k) ----
    #pragma unroll
    for (int i = 0; i < 8; ++i) {
        float m = mval[i]; int id = midx[i];
        #pragma unroll
        for (int mask = 1; mask <= 8; mask <<= 1) {
            float m2 = __shfl_xor(m, mask, 64);
            int   i2 = __shfl_xor(id, mask, 64);
            if (m2 < m || (m2 == m && i2 < id)) { m = m2; id = i2; }
        }
        if (kl == 0) { md_sh[ng*8 + i] = m; idx_sh[ng*8 + i] = id; }
    }
    __syncthreads();

    // ---- histogram + error sum (min distance == ||z-e||^2) ----
    if (t < 128) atomicAdd(&counts[idx_sh[t]], 1u);
    if (t < 64) {
        float s = md_sh[t] + md_sh[t + 64];
        #pragma unroll
        for (int off = 32; off >= 1; off >>= 1) s += __shfl_down(s, off, 64);
        if (t == 0) atomicAdd(errsum, s);
    }

    // ---- epilogue: out = z + (q - z), exact ref rounding ----
    {
        const int x  = t & 127;
        const int cg = t >> 7;
        const int xo = ZOFF(x);
        const int idx = idx_sh[x];
        const float* er = emb + idx * 64;
        float* ob = out + bb * (64 * HW) + hw0 + x;
        #pragma unroll
        for (int cq = 0; cq < 8; ++cq) {
            const int c  = cg * 32 + cq * 4;
            const int dc = c >> 2;
            float4 e4 = *(const float4*)&er[c];
            float4 z4 = *(const float4*)&zt[dc * ZPLANE + xo];
            ob[(c+0) * HW] = z4.x + (e4.x - z4.x);
            ob[(c+1) * HW] = z4.y + (e4.y - z4.y);
            ob[(c+2) * HW] = z4.z + (e4.z - z4.z);
            ob[(c+3) * HW] = z4.w + (e4.w - z4.w);
        }
    }
}

// ---------------- finalize: scalars ----------------
__global__ __launch_bounds__(256) void vq_fin(const unsigned int* __restrict__ counts,
                                              const float* __restrict__ errsum,
                                              float* __restrict__ scal)
{
    __shared__ float part[4];
    const int t = threadIdx.x;
    float s = 0.0f;
    for (int k = t; k < NEMB; k += 256) {
        float p = (float)counts[k] * (1.0f / 65536.0f);
        s += p * logf(p + 1e-10f);
    }
    #pragma unroll
    for (int off = 32; off >= 1; off >>= 1) s += __shfl_down(s, off, 64);
    if ((t & 63) == 0) part[t >> 6] = s;
    __syncthreads();
    if (t == 0) {
        float tot = (part[0] + part[1]) + (part[2] + part[3]);
        float es  = *errsum;
        scal[0] = 1.25f * (es * (1.0f / 4194304.0f));  // loss = 1.25 * mse
        scal[1] = expf(-tot);                          // perplexity
        scal[2] = es * (1.0f / 65536.0f);              // avg_error
    }
}

extern "C" void kernel_launch(void* const* d_in, const int* in_sizes, int n_in,
                              void* d_out, int out_size, void* d_ws, size_t ws_size,
                              hipStream_t stream) {
    const float* z   = (const float*)d_in[0];
    const float* emb = (const float*)d_in[1];
    float* out = (float*)d_out;
    unsigned int* counts = (unsigned int*)d_ws;
    float* errsum = (float*)((char*)d_ws + 4096);
    float* enorm  = (float*)((char*)d_ws + 8192);

    vq_init<<<8, 128, 0, stream>>>(emb, counts, errsum, enorm);
    vq_main<<<512, 256, 0, stream>>>(z, emb, enorm, out, counts, errsum);
    vq_fin<<<1, 256, 0, stream>>>(counts, errsum, out + 4194304);
}

// Round 5
// 125.469 us; speedup vs baseline: 14.1234x; 1.1948x over previous
//
#include <hip/hip_runtime.h>
#include <stdint.h>

#define HW   4096      // 64*64 spatial per batch
#define NEMB 1024

typedef float f2 __attribute__((ext_vector_type(2)));
typedef float f4 __attribute__((ext_vector_type(4)));

// packed fp32 FMA: lo/hi acc chains stay independent + sequential (bit-exact).
// PKL: b-operand broadcasts LO word of E-pair; PKH: broadcasts HI word.
#define PKL(A, Z, E) asm("v_pk_fma_f32 %0, %1, %2, %0 op_sel_hi:[1,0,1]" : "+v"(A) : "v"(Z), "v"(E))
#define PKH(A, Z, E) asm("v_pk_fma_f32 %0, %1, %2, %0 op_sel:[0,1,0]"   : "+v"(A) : "v"(Z), "v"(E))

// direct global->LDS DMA, 16B per lane (linear dest = wave base + lane*16)
__device__ __forceinline__ void gload_lds16(const float* g, float* l) {
    __builtin_amdgcn_global_load_lds(
        (const __attribute__((address_space(1))) void*)(uintptr_t)g,
        (__attribute__((address_space(3))) void*)(uintptr_t)l, 16, 0, 0);
}

// ---------------- init: zero counts + errsum, precompute enorm ----------------
// numpy pairwise-8 accumulator order (verified bit-exact r1/r4).
__global__ __launch_bounds__(128) void vq_init(const float* __restrict__ emb,
                                               unsigned int* __restrict__ counts,
                                               float* __restrict__ errsum,
                                               float* __restrict__ enorm) {
    const int k = blockIdx.x * 128 + threadIdx.x;
    counts[k] = 0u;
    if (k == 0) *errsum = 0.0f;
    const float* e = emb + k * 64;
    float a[8] = {0,0,0,0,0,0,0,0};
    #pragma unroll
    for (int c = 0; c < 16; ++c) {
        f4 v = *(const f4*)(e + c * 4);
        a[(4*c+0) & 7] += v.x * v.x;
        a[(4*c+1) & 7] += v.y * v.y;
        a[(4*c+2) & 7] += v.z * v.z;
        a[(4*c+3) & 7] += v.w * v.w;
    }
    enorm[k] = ((a[0]+a[1]) + (a[2]+a[3])) + ((a[4]+a[5]) + (a[6]+a[7]));
}

// ---------------- main ----------------
// grid 512 x 256. Block: 128 samples, 8 k-tiles of 128 embeddings.
__global__ __launch_bounds__(256, 2)
void vq_main(const float* __restrict__ z, const float* __restrict__ emb,
             const float* __restrict__ enorm,
             float* __restrict__ out, unsigned int* __restrict__ counts,
             float* __restrict__ errsum)
{
    __shared__ __attribute__((aligned(16))) float zt[64 * 128];  // [d][x], linear
    __shared__ __attribute__((aligned(16))) float et[128 * 64];  // row r: slot s = chunk s^(r>>3)
    __shared__ __attribute__((aligned(16))) float en_all[NEMB];
    __shared__ float znorm_s[128];
    __shared__ float md_sh[128];
    __shared__ int   idx_sh[128];

    const int t   = threadIdx.x;
    const int n0  = blockIdx.x * 128;
    const int bb  = n0 >> 12;        // batch index
    const int hw0 = n0 & 4095;
    const float* zb = z + bb * (64 * HW) + hw0;   // + d*HW + x

    // ---- issue et tile 0 DMA (pre-swizzled source, linear dest) ----
    #pragma unroll
    for (int it = 0; it < 8; ++it) {
        const int p  = it * 256 + t;             // float4 position 0..2047
        const int r  = p >> 4;                   // row 0..127
        const int dc = (p & 15) ^ (r >> 3);      // inverse swizzle on SOURCE
        gload_lds16(emb + r * 64 + dc * 4, et + p * 4);
    }
    // ---- issue zt DMA: global [d][x] rows -> LDS [d][x] linear ----
    #pragma unroll
    for (int it = 0; it < 8; ++it) {
        const int p = it * 256 + t;              // float4 position 0..2047
        const int d = p >> 5;
        const int x = (p & 31) * 4;
        gload_lds16(zb + d * HW + x, zt + p * 4);
    }
    // ---- stage all 1024 enorms ----
    *(f4*)&en_all[t * 4] = *(const f4*)&enorm[t * 4];
    __syncthreads();   // DMA drained: zt + et0 + en_all visible

    // ---- znorm, numpy pairwise-8 order (column walk, 2-way = free) ----
    if (t < 128) {
        float a[8] = {0,0,0,0,0,0,0,0};
        #pragma unroll
        for (int d = 0; d < 64; ++d) {
            float v = zt[d * 128 + t];
            a[d & 7] += v * v;
        }
        znorm_s[t] = ((a[0]+a[1]) + (a[2]+a[3])) + ((a[4]+a[5]) + (a[6]+a[7]));
    }
    __syncthreads();

    const int kl = t & 15;   // k-lane (0..15)
    const int ng = t >> 4;   // n-group (0..15)
    const float* ep = et + kl * 512;        // row kl*8+j at +j*64; swizzle = kl
    const float* zp = zt + ng * 8;          // + d*128 + pair offsets

    float zn[8];
    #pragma unroll
    for (int i = 0; i < 8; ++i) zn[i] = znorm_s[ng * 8 + i];

    float mval[8];
    int   midx[8];
    #pragma unroll
    for (int i = 0; i < 8; ++i) { mval[i] = __builtin_inff(); midx[i] = 0; }

    #pragma unroll 1
    for (int kt = 0; kt < 8; ++kt) {
        const int kbase = kt << 7;

        float en[8];
        {
            f4 ea = *(const f4*)&en_all[kbase + kl * 8];
            f4 eb = *(const f4*)&en_all[kbase + kl * 8 + 4];
            en[0]=ea.x; en[1]=ea.y; en[2]=ea.z; en[3]=ea.w;
            en[4]=eb.x; en[5]=eb.y; en[6]=eb.z; en[7]=eb.w;
        }

        f2 acc[4][8];
        #pragma unroll
        for (int ip = 0; ip < 4; ++ip)
            #pragma unroll
            for (int j = 0; j < 8; ++j) acc[ip][j] = (f2)(0.0f);

        // dot: packed over sample-pairs; each acc half is the ascending-d
        // sequential IEEE-FMA chain (bit-exact vs numpy/BLAS reference).
        #pragma unroll 4
        for (int dc = 0; dc < 16; ++dc) {
            const int eo = ((dc ^ kl) << 2);
            f4 ef[8];
            #pragma unroll
            for (int j = 0; j < 8; ++j) ef[j] = *(const f4*)(ep + j * 64 + eo);
            #pragma unroll
            for (int ds = 0; ds < 4; ++ds) {
                const float* zr = zp + (dc * 4 + ds) * 128;
                f2 z0 = *(const f2*)(zr + 0);
                f2 z1 = *(const f2*)(zr + 2);
                f2 z2 = *(const f2*)(zr + 4);
                f2 z3 = *(const f2*)(zr + 6);
                #pragma unroll
                for (int j = 0; j < 8; ++j) {
                    f2 e2 = (ds < 2) ? __builtin_shufflevector(ef[j], ef[j], 0, 1)
                                     : __builtin_shufflevector(ef[j], ef[j], 2, 3);
                    if ((ds & 1) == 0) {
                        PKL(acc[0][j], z0, e2); PKL(acc[1][j], z1, e2);
                        PKL(acc[2][j], z2, e2); PKL(acc[3][j], z3, e2);
                    } else {
                        PKH(acc[0][j], z0, e2); PKH(acc[1][j], z1, e2);
                        PKH(acc[2][j], z2, e2); PKH(acc[3][j], z3, e2);
                    }
                }
            }
        }

        __syncthreads();   // all waves done READING et[kt]
        if (kt < 7) {      // issue et[kt+1] DMA; latency hides under argmin tail
            #pragma unroll
            for (int it = 0; it < 8; ++it) {
                const int p  = it * 256 + t;
                const int r  = p >> 4;
                const int dc = (p & 15) ^ (r >> 3);
                gload_lds16(emb + (kbase + 128 + r) * 64 + dc * 4, et + p * 4);
            }
        }

        // distances + running argmin (ascending k, strict < => first-index tie-break)
        #pragma unroll
        for (int j = 0; j < 8; ++j) {
            const int kg = kbase + kl * 8 + j;
            #pragma unroll
            for (int ip = 0; ip < 4; ++ip) {
                {
                    const float tt   = zn[2*ip] + en[j];
                    const float dist = fmaf(-2.0f, acc[ip][j][0], tt);
                    if (dist < mval[2*ip]) { mval[2*ip] = dist; midx[2*ip] = kg; }
                }
                {
                    const float tt   = zn[2*ip+1] + en[j];
                    const float dist = fmaf(-2.0f, acc[ip][j][1], tt);
                    if (dist < mval[2*ip+1]) { mval[2*ip+1] = dist; midx[2*ip+1] = kg; }
                }
            }
        }

        __syncthreads();   // drains vmcnt -> et[kt+1] ready
    }

    // ---- cross-lane argmin over 16 k-lanes (tie-break: smaller k) ----
    #pragma unroll
    for (int i = 0; i < 8; ++i) {
        float m = mval[i]; int id = midx[i];
        #pragma unroll
        for (int mask = 1; mask <= 8; mask <<= 1) {
            float m2 = __shfl_xor(m, mask, 64);
            int   i2 = __shfl_xor(id, mask, 64);
            if (m2 < m || (m2 == m && i2 < id)) { m = m2; id = i2; }
        }
        if (kl == 0) { md_sh[ng*8 + i] = m; idx_sh[ng*8 + i] = id; }
    }
    __syncthreads();

    // ---- histogram + error sum (min distance == ||z-e||^2) ----
    if (t < 128) atomicAdd(&counts[idx_sh[t]], 1u);
    if (t < 64) {
        float s = md_sh[t] + md_sh[t + 64];
        #pragma unroll
        for (int off = 32; off >= 1; off >>= 1) s += __shfl_down(s, off, 64);
        if (t == 0) atomicAdd(errsum, s);
    }

    // ---- epilogue: out = z + (q - z), exact ref rounding ----
    {
        const int x  = t & 127;
        const int cg = t >> 7;
        const int idx = idx_sh[x];
        const float* er = emb + idx * 64;
        float* ob = out + bb * (64 * HW) + hw0 + x;
        #pragma unroll
        for (int cq = 0; cq < 8; ++cq) {
            const int c = cg * 32 + cq * 4;
            f4 e4 = *(const f4*)&er[c];
            float z0 = zt[(c+0) * 128 + x];
            float z1 = zt[(c+1) * 128 + x];
            float z2 = zt[(c+2) * 128 + x];
            float z3 = zt[(c+3) * 128 + x];
            ob[(c+0) * HW] = z0 + (e4.x - z0);
            ob[(c+1) * HW] = z1 + (e4.y - z1);
            ob[(c+2) * HW] = z2 + (e4.z - z2);
            ob[(c+3) * HW] = z3 + (e4.w - z3);
        }
    }
}

// ---------------- finalize: scalars ----------------
__global__ __launch_bounds__(256) void vq_fin(const unsigned int* __restrict__ counts,
                                              const float* __restrict__ errsum,
                                              float* __restrict__ scal)
{
    __shared__ float part[4];
    const int t = threadIdx.x;
    float s = 0.0f;
    for (int k = t; k < NEMB; k += 256) {
        float p = (float)counts[k] * (1.0f / 65536.0f);
        s += p * logf(p + 1e-10f);
    }
    #pragma unroll
    for (int off = 32; off >= 1; off >>= 1) s += __shfl_down(s, off, 64);
    if ((t & 63) == 0) part[t >> 6] = s;
    __syncthreads();
    if (t == 0) {
        float tot = (part[0] + part[1]) + (part[2] + part[3]);
        float es  = *errsum;
        scal[0] = 1.25f * (es * (1.0f / 4194304.0f));  // loss = 1.25 * mse
        scal[1] = expf(-tot);                          // perplexity
        scal[2] = es * (1.0f / 65536.0f);              // avg_error
    }
}

extern "C" void kernel_launch(void* const* d_in, const int* in_sizes, int n_in,
                              void* d_out, int out_size, void* d_ws, size_t ws_size,
                              hipStream_t stream) {
    const float* z   = (const float*)d_in[0];
    const float* emb = (const float*)d_in[1];
    float* out = (float*)d_out;
    unsigned int* counts = (unsigned int*)d_ws;
    float* errsum = (float*)((char*)d_ws + 4096);
    float* enorm  = (float*)((char*)d_ws + 8192);

    vq_init<<<8, 128, 0, stream>>>(emb, counts, errsum, enorm);
    vq_main<<<512, 256, 0, stream>>>(z, emb, enorm, out, counts, errsum);
    vq_fin<<<1, 256, 0, stream>>>(counts, errsum, out + 4194304);
}